// Round 8
// baseline (251.290 us; speedup 1.0000x reference)
//
#include <hip/hip_runtime.h>
#include <math.h>

constexpr int NN  = 50000;   // nodes
constexpr int NE  = 800000;  // edges
constexpr int IND = 128;     // input dim
constexpr int HCD = 128;     // heads*channels

// bucketed CSR-fill geometry
constexpr int NBKT = 16;               // dst-range buckets
constexpr int NPB  = NN / NBKT;        // 3125 nodes per bucket
constexpr int BCAP = 65536;            // staging capacity per bucket (mean 50k)
constexpr int BE   = 512;              // edges per bucket_kernel block
constexpr int B1B  = (NE + BE - 1) / BE;   // 1563 blocks

typedef __attribute__((ext_vector_type(8))) short bf16x8;
typedef __attribute__((ext_vector_type(4))) float f32x4;

__device__ __forceinline__ void splitbf(float f, unsigned short &h, unsigned short &lo) {
    unsigned u = __float_as_uint(f);
    h = (unsigned short)(u >> 16);
    float fh = __uint_as_float(u & 0xffff0000u);
    lo = (unsigned short)(__float_as_uint(f - fh) >> 16);
}
__device__ __forceinline__ unsigned short bf16rne(float f) {
    unsigned u = __float_as_uint(f);
    u += 0x7fffu + ((u >> 16) & 1u);
    return (unsigned short)(u >> 16);
}

// ---------------------------------------------------------------------------
// K1: MFMA split-bf16 GEMM.  grid.y==0: xl_bf16 = bf16(x@Wl + bl)
//                            grid.y==1: xr      = x@Wr + br  (fp32)
// ---------------------------------------------------------------------------
constexpr int BM = 128;
constexpr int BK = 64;

__global__ __launch_bounds__(256) void gemm_mfma(
    const float* __restrict__ x, const float* __restrict__ Wl,
    const float* __restrict__ Wr, const float* __restrict__ bl,
    const float* __restrict__ br, unsigned short* __restrict__ xlbf,
    float* __restrict__ xr)
{
    extern __shared__ char smem[];      // 48 KB
    char* Ah = smem;                    // [128][64] bf16
    char* Al = smem + 16384;
    char* Bh = smem + 32768;            // [c=128][k=64] bf16 (W transposed)

    const int tid = threadIdx.x;
    const float* W  = blockIdx.y ? Wr : Wl;
    const float* bv = blockIdx.y ? br : bl;
    const int bn = blockIdx.x * BM;

    const int l   = tid & 63;
    const int wid = tid >> 6;
    const int wr  = (wid >> 1) * 64;
    const int wc  = (wid & 1) * 64;
    const int lr  = l & 15;
    const int kg  = l >> 4;

    f32x4 acc[4][4];
#pragma unroll
    for (int s = 0; s < 4; ++s)
#pragma unroll
        for (int f = 0; f < 4; ++f) acc[s][f] = (f32x4){0.f, 0.f, 0.f, 0.f};

    const int cB  = tid & 127;
    const int khB = tid >> 7;

    for (int ki = 0; ki < 2; ++ki) {
#pragma unroll
        for (int r = 0; r < 8; ++r) {
            int g = tid + r * 256;
            int row = g >> 4, k4 = g & 15;
            int node = bn + row;
            float4 v = make_float4(0.f, 0.f, 0.f, 0.f);
            if (node < NN) v = *(const float4*)&x[node * IND + ki * BK + k4 * 4];
            unsigned short h0, h1, h2, h3, q0, q1, q2, q3;
            splitbf(v.x, h0, q0); splitbf(v.y, h1, q1);
            splitbf(v.z, h2, q2); splitbf(v.w, h3, q3);
            int off = (row * BK + k4 * 4) * 2;
            int swz = off ^ ((row & 7) << 4);
            *(ushort4*)(Ah + swz) = make_ushort4(h0, h1, h2, h3);
            *(ushort4*)(Al + swz) = make_ushort4(q0, q1, q2, q3);
        }
#pragma unroll
        for (int r = 0; r < 8; ++r) {
            int kb = r * 8 + khB * 4;
            float f0 = W[(ki * BK + kb + 0) * HCD + cB];
            float f1 = W[(ki * BK + kb + 1) * HCD + cB];
            float f2 = W[(ki * BK + kb + 2) * HCD + cB];
            float f3 = W[(ki * BK + kb + 3) * HCD + cB];
            int off = (cB * BK + kb) * 2;
            int swz = off ^ ((cB & 7) << 4);
            *(ushort4*)(Bh + swz) = make_ushort4(bf16rne(f0), bf16rne(f1),
                                                 bf16rne(f2), bf16rne(f3));
        }
        __syncthreads();
#pragma unroll
        for (int kk = 0; kk < 2; ++kk) {
            bf16x8 Bfh[4];
#pragma unroll
            for (int f = 0; f < 4; ++f) {
                int c = wc + f * 16 + lr;
                int swz = (c * 128 + kk * 64 + kg * 16) ^ ((c & 7) << 4);
                Bfh[f] = *(const bf16x8*)(Bh + swz);
            }
#pragma unroll
            for (int s = 0; s < 4; ++s) {
                int row = wr + s * 16 + lr;
                int swz = (row * 128 + kk * 64 + kg * 16) ^ ((row & 7) << 4);
                bf16x8 Afh = *(const bf16x8*)(Ah + swz);
                bf16x8 Afl = *(const bf16x8*)(Al + swz);
#pragma unroll
                for (int f = 0; f < 4; ++f) {
                    acc[s][f] = __builtin_amdgcn_mfma_f32_16x16x32_bf16(Afh, Bfh[f], acc[s][f], 0, 0, 0);
                    acc[s][f] = __builtin_amdgcn_mfma_f32_16x16x32_bf16(Afl, Bfh[f], acc[s][f], 0, 0, 0);
                }
            }
        }
        __syncthreads();
    }
#pragma unroll
    for (int s = 0; s < 4; ++s)
#pragma unroll
        for (int f = 0; f < 4; ++f) {
            int c = wc + f * 16 + lr;
            float bb = bv[c];
#pragma unroll
            for (int j = 0; j < 4; ++j) {
                int r = bn + wr + s * 16 + kg * 4 + j;
                if (r >= NN) continue;
                float v = acc[s][f][j] + bb;
                if (blockIdx.y) xr[r * HCD + c] = v;
                else            xlbf[r * HCD + c] = bf16rne(v);
            }
        }
}

// ---------------------------------------------------------------------------
// K2: bucket scatter + degree count. 512 edges/block (1563 blocks -> good
// TLP). LDS-counted per-bucket grant (1 global atomic/bucket/block), then
// compacted packed-int2 (src|dloc<<17, ea) into per-bucket staging.
// ---------------------------------------------------------------------------
__global__ __launch_bounds__(256) void bucket_kernel(
    const int* __restrict__ src, const int* __restrict__ dst,
    const float* __restrict__ ea, int* __restrict__ gcur,
    int* __restrict__ deg, int2* __restrict__ stg)
{
    __shared__ int cnt[NBKT], base[NBKT];
    const int tid = threadIdx.x;
    if (tid < NBKT) cnt[tid] = 0;
    __syncthreads();

    const int e0 = blockIdx.x * BE;
    int w0[2], w1[2]; int nb[2];
#pragma unroll
    for (int j = 0; j < 2; ++j) {
        int e = e0 + j * 256 + tid;
        bool ok = e < NE;
        int s_ = ok ? src[e] : 0;
        int d_ = ok ? dst[e] : 0;
        float a_ = ok ? ea[e] : 0.f;
        int b  = d_ / NPB;
        int dl = d_ - b * NPB;
        w0[j] = s_ | (dl << 17);
        w1[j] = __float_as_int(a_);
        nb[j] = ok ? b : -1;
        if (ok) atomicAdd(&cnt[b], 1);
    }
    __syncthreads();
    if (tid < NBKT) {
        base[tid] = atomicAdd(&gcur[tid * 16], cnt[tid]);
        cnt[tid] = 0;                    // reuse as local cursor
    }
    __syncthreads();
#pragma unroll
    for (int j = 0; j < 2; ++j) {
        if (nb[j] >= 0) {
            int slot = base[nb[j]] + atomicAdd(&cnt[nb[j]], 1);
            stg[nb[j] * BCAP + slot] = make_int2(w0[j], w1[j]);
            atomicAdd(&deg[nb[j] * NPB + (w0[j] >> 17)], 1);
        }
    }
}

// ---------------------------------------------------------------------------
// K3a/b/c: 3-phase coalesced exclusive scan of deg -> off
// ---------------------------------------------------------------------------
constexpr int SB = (NN + 255) / 256;   // 196 scan blocks

__global__ __launch_bounds__(256) void scan1(const int* __restrict__ deg,
                                             int* __restrict__ bsum)
{
    __shared__ int red[4];
    int idx = blockIdx.x * 256 + threadIdx.x;
    int v = (idx < NN) ? deg[idx] : 0;
    for (int d = 32; d; d >>= 1) v += __shfl_down(v, d);
    if ((threadIdx.x & 63) == 0) red[threadIdx.x >> 6] = v;
    __syncthreads();
    if (threadIdx.x == 0) bsum[blockIdx.x] = red[0] + red[1] + red[2] + red[3];
}

__global__ __launch_bounds__(256) void scan2(const int* __restrict__ bsum,
                                             int* __restrict__ boff)
{
    __shared__ int t[256];
    int tid = threadIdx.x;
    int v = (tid < SB) ? bsum[tid] : 0;
    t[tid] = v;
    __syncthreads();
    for (int d = 1; d < 256; d <<= 1) {
        int u = (tid >= d) ? t[tid - d] : 0;
        __syncthreads();
        t[tid] += u;
        __syncthreads();
    }
    boff[tid] = t[tid] - v;
}

__global__ __launch_bounds__(256) void scan3(const int* __restrict__ deg,
                                             const int* __restrict__ boff,
                                             int* __restrict__ off)
{
    __shared__ int t[256];
    int tid = threadIdx.x;
    int idx = blockIdx.x * 256 + tid;
    int v = (idx < NN) ? deg[idx] : 0;
    t[tid] = v;
    __syncthreads();
    for (int d = 1; d < 256; d <<= 1) {
        int u = (tid >= d) ? t[tid - d] : 0;
        __syncthreads();
        t[tid] += u;
        __syncthreads();
    }
    int excl = t[tid] - v + boff[blockIdx.x];
    if (idx < NN) off[idx] = excl;
    if (idx == NN - 1) off[NN] = excl + v;
}

// ---------------------------------------------------------------------------
// K4: CSR fill from staging. Block i -> bucket (i&7)*2 + ((i>>3)&1), so all
// blocks on one XCD (round-robin dispatch) scatter into the same ~400KB csr
// window -> stores merge in that XCD's L2.
// ---------------------------------------------------------------------------
__global__ __launch_bounds__(256) void csrfill_kernel(
    const int2* __restrict__ stg, const int* __restrict__ gcur,
    const int* __restrict__ off, int* __restrict__ cursor,
    int2* __restrict__ csr)
{
    const int i = blockIdx.x;                 // 0..255
    const int b = (i & 7) * 2 + ((i >> 3) & 1);
    const int chunk = i >> 4;                 // 0..15
    const int count = gcur[b * 16];
#pragma unroll
    for (int j = 0; j < 16; ++j) {
        int sl = chunk * (BCAP / 16) + j * 256 + threadIdx.x;
        if (sl < count) {
            int2 v = stg[b * BCAP + sl];
            int d = b * NPB + ((unsigned)v.x >> 17);
            int pos = off[d] + atomicAdd(&cursor[d], 1);
            csr[pos] = make_int2(v.x & 0x1ffff, v.y);
        }
    }
}

// ---------------------------------------------------------------------------
// K5: node kernel, 1 wave = 1 node. Lane l = 16*g + i: group g (0..3)
// processes edge quad-slot g, lane i owns channels [8i, 8i+8).
// ---------------------------------------------------------------------------
__global__ __launch_bounds__(256) void node_kernel(
    const unsigned short* __restrict__ xlbf, const float* __restrict__ xr,
    const float* __restrict__ We, const float* __restrict__ att,
    const int* __restrict__ off, const int2* __restrict__ csr,
    float* __restrict__ out_pre)
{
    const int n = blockIdx.x * 4 + (threadIdx.x >> 6);
    if (n >= NN) return;
    const int l  = threadIdx.x & 63;
    const int g  = l >> 4;
    const int i  = l & 15;
    const int c0 = i * 8;

    float wev[8], atv[8], xrv[8];
    {
        float4 a = *(const float4*)&We[c0],  b = *(const float4*)&We[c0 + 4];
        wev[0]=a.x; wev[1]=a.y; wev[2]=a.z; wev[3]=a.w;
        wev[4]=b.x; wev[5]=b.y; wev[6]=b.z; wev[7]=b.w;
        float4 c = *(const float4*)&att[c0], d = *(const float4*)&att[c0 + 4];
        atv[0]=c.x; atv[1]=c.y; atv[2]=c.z; atv[3]=c.w;
        atv[4]=d.x; atv[5]=d.y; atv[6]=d.z; atv[7]=d.w;
        float4 p = *(const float4*)&xr[(size_t)n * HCD + c0];
        float4 q = *(const float4*)&xr[(size_t)n * HCD + c0 + 4];
        xrv[0]=p.x; xrv[1]=p.y; xrv[2]=p.z; xrv[3]=p.w;
        xrv[4]=q.x; xrv[5]=q.y; xrv[6]=q.z; xrv[7]=q.w;
    }

    const int s = off[n], e = off[n + 1];
    if (s == e) {
        if (g == 0) {
            float4 z = make_float4(0.f, 0.f, 0.f, 0.f);
            *(float4*)&out_pre[(size_t)n * HCD + c0] = z;
            *(float4*)&out_pre[(size_t)n * HCD + c0 + 4] = z;
        }
        return;
    }

    float mx = -3.0e38f, sm = 0.f;
    float acc[8];
#pragma unroll
    for (int c = 0; c < 8; ++c) acc[c] = 0.f;

    int k = s;
    int2 c2; uint4 xb; bool v;
    {
        int idx = k + g; if (idx > e - 1) idx = e - 1;
        c2 = csr[idx];
        xb = *(const uint4*)&xlbf[(size_t)c2.x * HCD + c0];
        v  = (k + g) < e;
    }

    for (; k < e; k += 4) {
        int2 c2n; uint4 xbn; bool vn;
        {
            int kn = k + 4 + g; int idx = kn; if (idx > e - 1) idx = e - 1;
            c2n = csr[idx];
            xbn = *(const uint4*)&xlbf[(size_t)c2n.x * HCD + c0];
            vn  = kn < e;
        }
        float xv[8];
        xv[0] = __uint_as_float(xb.x << 16);
        xv[1] = __uint_as_float(xb.x & 0xffff0000u);
        xv[2] = __uint_as_float(xb.y << 16);
        xv[3] = __uint_as_float(xb.y & 0xffff0000u);
        xv[4] = __uint_as_float(xb.z << 16);
        xv[5] = __uint_as_float(xb.z & 0xffff0000u);
        xv[6] = __uint_as_float(xb.w << 16);
        xv[7] = __uint_as_float(xb.w & 0xffff0000u);

        float ea = __int_as_float(c2.y);
        float p = 0.f;
#pragma unroll
        for (int c = 0; c < 8; ++c) {
            float m = fmaf(ea, wev[c], xv[c] + xrv[c]);
            m = fmaxf(m, 0.2f * m);                    // leaky_relu slope 0.2
            p = fmaf(m, atv[c], p);
        }
        p += __shfl_xor(p, 1);                          // 4-lane head reduce
        p += __shfl_xor(p, 2);
        if (!v) p = -1.0e30f;

        if (__any(p > mx + 8.f)) {
            float nm = fmaxf(mx, p);
            float sc = __expf(mx - nm);
            sm *= sc;
#pragma unroll
            for (int c = 0; c < 8; ++c) acc[c] *= sc;
            mx = nm;
        }
        float ev = v ? __expf(p - mx) : 0.f;
        sm += ev;
#pragma unroll
        for (int c = 0; c < 8; ++c) acc[c] = fmaf(ev, xv[c], acc[c]);

        c2 = c2n; xb = xbn; v = vn;
    }

    float M = fmaxf(mx, __shfl_xor(mx, 16));
    M = fmaxf(M, __shfl_xor(M, 32));
    float sc = __expf(mx - M);
    float smT = sm * sc;
    smT += __shfl_xor(smT, 16);
    smT += __shfl_xor(smT, 32);
    float inv = 1.f / (smT + 1e-16f);
    float o[8];
#pragma unroll
    for (int c = 0; c < 8; ++c) {
        float a = acc[c] * sc;
        a += __shfl_xor(a, 16);
        a += __shfl_xor(a, 32);
        o[c] = a * inv;
    }
    if (g == 0) {
        *(float4*)&out_pre[(size_t)n * HCD + c0]     = make_float4(o[0], o[1], o[2], o[3]);
        *(float4*)&out_pre[(size_t)n * HCD + c0 + 4] = make_float4(o[4], o[5], o[6], o[7]);
    }
}

// ---------------------------------------------------------------------------
// K6: BN statistics (per-channel sum & sumsq)
// ---------------------------------------------------------------------------
__global__ __launch_bounds__(128) void bnstat_kernel(const float* __restrict__ out_pre,
                                                     float* __restrict__ stats)
{
    const int t = threadIdx.x;
    float s = 0.f, q = 0.f;
    for (int n = blockIdx.x; n < NN; n += gridDim.x) {
        float v = out_pre[n * HCD + t];
        s += v; q += v * v;
    }
    atomicAdd(&stats[t], s);
    atomicAdd(&stats[HCD + t], q);
}

// ---------------------------------------------------------------------------
// K7: normalize + affine + ELU  (float4)
// ---------------------------------------------------------------------------
__global__ __launch_bounds__(256) void bn_elu_kernel(
    const float* __restrict__ out_pre, const float* __restrict__ stats,
    const float* __restrict__ gamma, const float* __restrict__ beta,
    float* __restrict__ out)
{
    int i4 = blockIdx.x * 256 + threadIdx.x;
    if (i4 >= NN * HCD / 4) return;
    int c4 = (i4 & 31) * 4;
    float4 v = *(const float4*)&out_pre[i4 * 4];
    float o[4] = {v.x, v.y, v.z, v.w};
#pragma unroll
    for (int j = 0; j < 4; ++j) {
        int c = c4 + j;
        float mean = stats[c] * (1.f / NN);
        float var  = stats[HCD + c] * (1.f / NN) - mean * mean;
        float inv  = rsqrtf(var + 1e-5f);
        float t = (o[j] - mean) * inv * gamma[c] + beta[c];
        o[j] = (t > 0.f) ? t : expm1f(t);
    }
    *(float4*)&((float*)out)[i4 * 4] = make_float4(o[0], o[1], o[2], o[3]);
}

// ---------------------------------------------------------------------------
extern "C" void kernel_launch(void* const* d_in, const int* in_sizes, int n_in,
                              void* d_out, int out_size, void* d_ws, size_t ws_size,
                              hipStream_t stream)
{
    (void)in_sizes; (void)n_in; (void)out_size; (void)ws_size;
    const float* x    = (const float*)d_in[0];
    const int*   ei   = (const int*)  d_in[1];
    const float* ea   = (const float*)d_in[2];
    const float* Wl   = (const float*)d_in[3];
    const float* bl   = (const float*)d_in[4];
    const float* Wr   = (const float*)d_in[5];
    const float* br   = (const float*)d_in[6];
    const float* We   = (const float*)d_in[7];
    const float* att  = (const float*)d_in[8];
    const float* gamma= (const float*)d_in[10];
    const float* beta = (const float*)d_in[11];
    float* out = (float*)d_out;

    char* wsb = (char*)d_ws;
    size_t o = 0;
    auto take = [&](size_t bytes) -> char* {
        char* p = wsb + o;
        o += (bytes + 255) & ~size_t(255);
        return p;
    };
    unsigned short* xlbf = (unsigned short*)take(sizeof(unsigned short) * NN * HCD);
    float* xr      = (float*)take(sizeof(float) * NN * HCD);
    float* out_pre = (float*)take(sizeof(float) * NN * HCD);
    int2*  csr     = (int2*) take(sizeof(int2)  * NE);
    int*   offs    = (int*)  take(sizeof(int)   * (NN + 1));
    int*   bsum    = (int*)  take(sizeof(int)   * 256);
    int*   boff    = (int*)  take(sizeof(int)   * 256);
    size_t zbytes  = sizeof(int) * NN * 2 + sizeof(float) * 2 * HCD
                   + sizeof(int) * NBKT * 16;
    char*  zbase   = take(zbytes);
    int*   deg     = (int*)zbase;
    int*   cursor  = deg + NN;
    float* stats   = (float*)(cursor + NN);
    int*   gcur    = (int*)(stats + 2 * HCD);

    // staging aliases out_pre (dead until node_kernel; csrfill finishes first)
    int2*  stg     = (int2*)out_pre;

    hipMemsetAsync(zbase, 0, zbytes, stream);

    const int* srcI = ei;
    const int* dstI = ei + NE;

    gemm_mfma<<<dim3((NN + BM - 1) / BM, 2), 256, 49152, stream>>>(
        x, Wl, Wr, bl, br, xlbf, xr);
    bucket_kernel<<<B1B, 256, 0, stream>>>(srcI, dstI, ea, gcur, deg, stg);
    scan1<<<SB, 256, 0, stream>>>(deg, bsum);
    scan2<<<1, 256, 0, stream>>>(bsum, boff);
    scan3<<<SB, 256, 0, stream>>>(deg, boff, offs);
    csrfill_kernel<<<256, 256, 0, stream>>>(stg, gcur, offs, cursor, csr);
    node_kernel<<<(NN + 3) / 4, 256, 0, stream>>>(xlbf, xr, We, att, offs, csr, out_pre);
    bnstat_kernel<<<512, 128, 0, stream>>>(out_pre, stats);
    bn_elu_kernel<<<(NN * HCD / 4 + 255) / 256, 256, 0, stream>>>(out_pre, stats,
                                                                  gamma, beta, out);
}

// Round 9
// 175.907 us; speedup vs baseline: 1.4285x; 1.4285x over previous
//
#include <hip/hip_runtime.h>
#include <math.h>

constexpr int NN  = 50000;   // nodes
constexpr int NE  = 800000;  // edges
constexpr int IND = 128;     // input dim
constexpr int HCD = 128;     // heads*channels

// fine-bucket CSR geometry
constexpr int NBKT = 250;              // dst-range buckets
constexpr int NPB  = 200;              // nodes per bucket (250*200 = 50000)
constexpr int BCAP = 4096;             // staging cap/bucket (mean 3200, 16 sigma)
constexpr int BE   = 2048;             // edges per bucket_kernel block
constexpr int EPT  = BE / 256;         // 8 edges per thread
constexpr int B1B  = (NE + BE - 1) / BE;   // 391 blocks

typedef __attribute__((ext_vector_type(8))) short bf16x8;
typedef __attribute__((ext_vector_type(4))) float f32x4;

__device__ __forceinline__ void splitbf(float f, unsigned short &h, unsigned short &lo) {
    unsigned u = __float_as_uint(f);
    h = (unsigned short)(u >> 16);
    float fh = __uint_as_float(u & 0xffff0000u);
    lo = (unsigned short)(__float_as_uint(f - fh) >> 16);
}
__device__ __forceinline__ unsigned short bf16rne(float f) {
    unsigned u = __float_as_uint(f);
    u += 0x7fffu + ((u >> 16) & 1u);
    return (unsigned short)(u >> 16);
}

// ---------------------------------------------------------------------------
// K1: MFMA split-bf16 GEMM.  grid.y==0: xl_bf16 = bf16(x@Wl + bl)
//                            grid.y==1: xr      = x@Wr + br  (fp32)
// ---------------------------------------------------------------------------
constexpr int BM = 128;
constexpr int BK = 64;

__global__ __launch_bounds__(256) void gemm_mfma(
    const float* __restrict__ x, const float* __restrict__ Wl,
    const float* __restrict__ Wr, const float* __restrict__ bl,
    const float* __restrict__ br, unsigned short* __restrict__ xlbf,
    float* __restrict__ xr)
{
    extern __shared__ char smem[];      // 48 KB
    char* Ah = smem;                    // [128][64] bf16
    char* Al = smem + 16384;
    char* Bh = smem + 32768;            // [c=128][k=64] bf16 (W transposed)

    const int tid = threadIdx.x;
    const float* W  = blockIdx.y ? Wr : Wl;
    const float* bv = blockIdx.y ? br : bl;
    const int bn = blockIdx.x * BM;

    const int l   = tid & 63;
    const int wid = tid >> 6;
    const int wr  = (wid >> 1) * 64;
    const int wc  = (wid & 1) * 64;
    const int lr  = l & 15;
    const int kg  = l >> 4;

    f32x4 acc[4][4];
#pragma unroll
    for (int s = 0; s < 4; ++s)
#pragma unroll
        for (int f = 0; f < 4; ++f) acc[s][f] = (f32x4){0.f, 0.f, 0.f, 0.f};

    const int cB  = tid & 127;
    const int khB = tid >> 7;

    for (int ki = 0; ki < 2; ++ki) {
#pragma unroll
        for (int r = 0; r < 8; ++r) {
            int g = tid + r * 256;
            int row = g >> 4, k4 = g & 15;
            int node = bn + row;
            float4 v = make_float4(0.f, 0.f, 0.f, 0.f);
            if (node < NN) v = *(const float4*)&x[node * IND + ki * BK + k4 * 4];
            unsigned short h0, h1, h2, h3, q0, q1, q2, q3;
            splitbf(v.x, h0, q0); splitbf(v.y, h1, q1);
            splitbf(v.z, h2, q2); splitbf(v.w, h3, q3);
            int off = (row * BK + k4 * 4) * 2;
            int swz = off ^ ((row & 7) << 4);
            *(ushort4*)(Ah + swz) = make_ushort4(h0, h1, h2, h3);
            *(ushort4*)(Al + swz) = make_ushort4(q0, q1, q2, q3);
        }
#pragma unroll
        for (int r = 0; r < 8; ++r) {
            int kb = r * 8 + khB * 4;
            float f0 = W[(ki * BK + kb + 0) * HCD + cB];
            float f1 = W[(ki * BK + kb + 1) * HCD + cB];
            float f2 = W[(ki * BK + kb + 2) * HCD + cB];
            float f3 = W[(ki * BK + kb + 3) * HCD + cB];
            int off = (cB * BK + kb) * 2;
            int swz = off ^ ((cB & 7) << 4);
            *(ushort4*)(Bh + swz) = make_ushort4(bf16rne(f0), bf16rne(f1),
                                                 bf16rne(f2), bf16rne(f3));
        }
        __syncthreads();
#pragma unroll
        for (int kk = 0; kk < 2; ++kk) {
            bf16x8 Bfh[4];
#pragma unroll
            for (int f = 0; f < 4; ++f) {
                int c = wc + f * 16 + lr;
                int swz = (c * 128 + kk * 64 + kg * 16) ^ ((c & 7) << 4);
                Bfh[f] = *(const bf16x8*)(Bh + swz);
            }
#pragma unroll
            for (int s = 0; s < 4; ++s) {
                int row = wr + s * 16 + lr;
                int swz = (row * 128 + kk * 64 + kg * 16) ^ ((row & 7) << 4);
                bf16x8 Afh = *(const bf16x8*)(Ah + swz);
                bf16x8 Afl = *(const bf16x8*)(Al + swz);
#pragma unroll
                for (int f = 0; f < 4; ++f) {
                    acc[s][f] = __builtin_amdgcn_mfma_f32_16x16x32_bf16(Afh, Bfh[f], acc[s][f], 0, 0, 0);
                    acc[s][f] = __builtin_amdgcn_mfma_f32_16x16x32_bf16(Afl, Bfh[f], acc[s][f], 0, 0, 0);
                }
            }
        }
        __syncthreads();
    }
#pragma unroll
    for (int s = 0; s < 4; ++s)
#pragma unroll
        for (int f = 0; f < 4; ++f) {
            int c = wc + f * 16 + lr;
            float bb = bv[c];
#pragma unroll
            for (int j = 0; j < 4; ++j) {
                int r = bn + wr + s * 16 + kg * 4 + j;
                if (r >= NN) continue;
                float v = acc[s][f][j] + bb;
                if (blockIdx.y) xr[r * HCD + c] = v;
                else            xlbf[r * HCD + c] = bf16rne(v);
            }
        }
}

// ---------------------------------------------------------------------------
// K2: bucket scatter. 2048 edges/block; LDS count -> one global grant per
// touched bucket -> compacted packed int2 (src|dloc<<17, ea) writes. Per-bin
// per-block runs ~64B contiguous. NO per-node atomics.
// ---------------------------------------------------------------------------
__global__ __launch_bounds__(256) void bucket_kernel(
    const int* __restrict__ src, const int* __restrict__ dst,
    const float* __restrict__ ea, int* __restrict__ gcur,
    int2* __restrict__ stg)
{
    __shared__ int cnt[NBKT], base[NBKT];
    const int tid = threadIdx.x;
    for (int j = tid; j < NBKT; j += 256) cnt[j] = 0;
    __syncthreads();

    const int e0 = blockIdx.x * BE;
    int w0[EPT], w1[EPT]; int nb[EPT];
#pragma unroll
    for (int j = 0; j < EPT; ++j) {
        int e = e0 + j * 256 + tid;
        bool ok = e < NE;
        int s_ = ok ? src[e] : 0;
        int d_ = ok ? dst[e] : 0;
        float a_ = ok ? ea[e] : 0.f;
        int b  = d_ / NPB;
        int dl = d_ - b * NPB;
        w0[j] = s_ | (dl << 17);
        w1[j] = __float_as_int(a_);
        nb[j] = ok ? b : -1;
        if (ok) atomicAdd(&cnt[b], 1);
    }
    __syncthreads();
    for (int j = tid; j < NBKT; j += 256) {
        base[j] = cnt[j] ? atomicAdd(&gcur[j], cnt[j]) : 0;
        cnt[j] = 0;                      // reuse as local cursor
    }
    __syncthreads();
#pragma unroll
    for (int j = 0; j < EPT; ++j) {
        if (nb[j] >= 0) {
            int slot = base[nb[j]] + atomicAdd(&cnt[nb[j]], 1);
            if (slot < BCAP)
                stg[nb[j] * BCAP + slot] = make_int2(w0[j], w1[j]);
        }
    }
}

// ---------------------------------------------------------------------------
// K3: exclusive scan of 250 bucket counts (single block)
// ---------------------------------------------------------------------------
__global__ __launch_bounds__(256) void bscan(const int* __restrict__ gcur,
                                             int* __restrict__ bbase,
                                             int* __restrict__ off)
{
    __shared__ int t[256];
    int tid = threadIdx.x;
    int v = (tid < NBKT) ? gcur[tid] : 0;
    t[tid] = v;
    __syncthreads();
    for (int d = 1; d < 256; d <<= 1) {
        int u = (tid >= d) ? t[tid - d] : 0;
        __syncthreads();
        t[tid] += u;
        __syncthreads();
    }
    if (tid < NBKT) bbase[tid] = t[tid] - v;
    if (tid == 0) off[NN] = NE;
}

// ---------------------------------------------------------------------------
// K4: per-bucket CSR build. One block per bucket: LDS histogram over its 200
// nodes -> LDS scan -> write off[] coalesced -> scatter csr within the
// bucket's ~25KB window (L2-resident, no global atomics).
// ---------------------------------------------------------------------------
__global__ __launch_bounds__(256) void csr_build(
    const int2* __restrict__ stg, const int* __restrict__ gcur,
    const int* __restrict__ bbase, int* __restrict__ off,
    int2* __restrict__ csr)
{
    __shared__ int hist[NPB], t[256], cur[NPB];
    const int b = blockIdx.x, tid = threadIdx.x;
    const int count = min(gcur[b], BCAP);
    const int base  = bbase[b];

    if (tid < NPB) { hist[tid] = 0; cur[tid] = 0; }
    __syncthreads();
    for (int sl = tid; sl < count; sl += 256)
        atomicAdd(&hist[(unsigned)stg[b * BCAP + sl].x >> 17], 1);
    __syncthreads();

    int hv = (tid < NPB) ? hist[tid] : 0;
    t[tid] = hv;
    __syncthreads();
    for (int d = 1; d < 256; d <<= 1) {
        int u = (tid >= d) ? t[tid - d] : 0;
        __syncthreads();
        t[tid] += u;
        __syncthreads();
    }
    if (tid < NPB) off[b * NPB + tid] = base + t[tid] - hv;   // exclusive
    __syncthreads();

    for (int sl = tid; sl < count; sl += 256) {
        int2 v = stg[b * BCAP + sl];
        int dl = (unsigned)v.x >> 17;
        int pos = base + (t[dl] - hist[dl]) + atomicAdd(&cur[dl], 1);
        csr[pos] = make_int2(v.x & 0x1ffff, v.y);
    }
}

// ---------------------------------------------------------------------------
// K5: node kernel, 1 wave = 1 node. Lane l = 16*g + i: group g (0..3)
// processes edge quad-slot g, lane i owns channels [8i, 8i+8).
// ---------------------------------------------------------------------------
__global__ __launch_bounds__(256) void node_kernel(
    const unsigned short* __restrict__ xlbf, const float* __restrict__ xr,
    const float* __restrict__ We, const float* __restrict__ att,
    const int* __restrict__ off, const int2* __restrict__ csr,
    float* __restrict__ out_pre)
{
    const int n = blockIdx.x * 4 + (threadIdx.x >> 6);
    if (n >= NN) return;
    const int l  = threadIdx.x & 63;
    const int g  = l >> 4;
    const int i  = l & 15;
    const int c0 = i * 8;

    float wev[8], atv[8], xrv[8];
    {
        float4 a = *(const float4*)&We[c0],  b = *(const float4*)&We[c0 + 4];
        wev[0]=a.x; wev[1]=a.y; wev[2]=a.z; wev[3]=a.w;
        wev[4]=b.x; wev[5]=b.y; wev[6]=b.z; wev[7]=b.w;
        float4 c = *(const float4*)&att[c0], d = *(const float4*)&att[c0 + 4];
        atv[0]=c.x; atv[1]=c.y; atv[2]=c.z; atv[3]=c.w;
        atv[4]=d.x; atv[5]=d.y; atv[6]=d.z; atv[7]=d.w;
        float4 p = *(const float4*)&xr[(size_t)n * HCD + c0];
        float4 q = *(const float4*)&xr[(size_t)n * HCD + c0 + 4];
        xrv[0]=p.x; xrv[1]=p.y; xrv[2]=p.z; xrv[3]=p.w;
        xrv[4]=q.x; xrv[5]=q.y; xrv[6]=q.z; xrv[7]=q.w;
    }

    const int s = off[n], e = off[n + 1];
    if (s == e) {
        if (g == 0) {
            float4 z = make_float4(0.f, 0.f, 0.f, 0.f);
            *(float4*)&out_pre[(size_t)n * HCD + c0] = z;
            *(float4*)&out_pre[(size_t)n * HCD + c0 + 4] = z;
        }
        return;
    }

    float mx = -3.0e38f, sm = 0.f;
    float acc[8];
#pragma unroll
    for (int c = 0; c < 8; ++c) acc[c] = 0.f;

    int k = s;
    int2 c2; uint4 xb; bool v;
    {
        int idx = k + g; if (idx > e - 1) idx = e - 1;
        c2 = csr[idx];
        xb = *(const uint4*)&xlbf[(size_t)c2.x * HCD + c0];
        v  = (k + g) < e;
    }

    for (; k < e; k += 4) {
        int2 c2n; uint4 xbn; bool vn;
        {
            int kn = k + 4 + g; int idx = kn; if (idx > e - 1) idx = e - 1;
            c2n = csr[idx];
            xbn = *(const uint4*)&xlbf[(size_t)c2n.x * HCD + c0];
            vn  = kn < e;
        }
        float xv[8];
        xv[0] = __uint_as_float(xb.x << 16);
        xv[1] = __uint_as_float(xb.x & 0xffff0000u);
        xv[2] = __uint_as_float(xb.y << 16);
        xv[3] = __uint_as_float(xb.y & 0xffff0000u);
        xv[4] = __uint_as_float(xb.z << 16);
        xv[5] = __uint_as_float(xb.z & 0xffff0000u);
        xv[6] = __uint_as_float(xb.w << 16);
        xv[7] = __uint_as_float(xb.w & 0xffff0000u);

        float ea = __int_as_float(c2.y);
        float p = 0.f;
#pragma unroll
        for (int c = 0; c < 8; ++c) {
            float m = fmaf(ea, wev[c], xv[c] + xrv[c]);
            m = fmaxf(m, 0.2f * m);                    // leaky_relu slope 0.2
            p = fmaf(m, atv[c], p);
        }
        p += __shfl_xor(p, 1);                          // 4-lane head reduce
        p += __shfl_xor(p, 2);
        if (!v) p = -1.0e30f;

        if (__any(p > mx + 8.f)) {
            float nm = fmaxf(mx, p);
            float sc = __expf(mx - nm);
            sm *= sc;
#pragma unroll
            for (int c = 0; c < 8; ++c) acc[c] *= sc;
            mx = nm;
        }
        float ev = v ? __expf(p - mx) : 0.f;
        sm += ev;
#pragma unroll
        for (int c = 0; c < 8; ++c) acc[c] = fmaf(ev, xv[c], acc[c]);

        c2 = c2n; xb = xbn; v = vn;
    }

    float M = fmaxf(mx, __shfl_xor(mx, 16));
    M = fmaxf(M, __shfl_xor(M, 32));
    float sc = __expf(mx - M);
    float smT = sm * sc;
    smT += __shfl_xor(smT, 16);
    smT += __shfl_xor(smT, 32);
    float inv = 1.f / (smT + 1e-16f);
    float o[8];
#pragma unroll
    for (int c = 0; c < 8; ++c) {
        float a = acc[c] * sc;
        a += __shfl_xor(a, 16);
        a += __shfl_xor(a, 32);
        o[c] = a * inv;
    }
    if (g == 0) {
        *(float4*)&out_pre[(size_t)n * HCD + c0]     = make_float4(o[0], o[1], o[2], o[3]);
        *(float4*)&out_pre[(size_t)n * HCD + c0 + 4] = make_float4(o[4], o[5], o[6], o[7]);
    }
}

// ---------------------------------------------------------------------------
// K6: BN statistics (per-channel sum & sumsq)
// ---------------------------------------------------------------------------
__global__ __launch_bounds__(128) void bnstat_kernel(const float* __restrict__ out_pre,
                                                     float* __restrict__ stats)
{
    const int t = threadIdx.x;
    float s = 0.f, q = 0.f;
    for (int n = blockIdx.x; n < NN; n += gridDim.x) {
        float v = out_pre[n * HCD + t];
        s += v; q += v * v;
    }
    atomicAdd(&stats[t], s);
    atomicAdd(&stats[HCD + t], q);
}

// ---------------------------------------------------------------------------
// K7: normalize + affine + ELU  (float4)
// ---------------------------------------------------------------------------
__global__ __launch_bounds__(256) void bn_elu_kernel(
    const float* __restrict__ out_pre, const float* __restrict__ stats,
    const float* __restrict__ gamma, const float* __restrict__ beta,
    float* __restrict__ out)
{
    int i4 = blockIdx.x * 256 + threadIdx.x;
    if (i4 >= NN * HCD / 4) return;
    int c4 = (i4 & 31) * 4;
    float4 v = *(const float4*)&out_pre[i4 * 4];
    float o[4] = {v.x, v.y, v.z, v.w};
#pragma unroll
    for (int j = 0; j < 4; ++j) {
        int c = c4 + j;
        float mean = stats[c] * (1.f / NN);
        float var  = stats[HCD + c] * (1.f / NN) - mean * mean;
        float inv  = rsqrtf(var + 1e-5f);
        float t = (o[j] - mean) * inv * gamma[c] + beta[c];
        o[j] = (t > 0.f) ? t : expm1f(t);
    }
    *(float4*)&((float*)out)[i4 * 4] = make_float4(o[0], o[1], o[2], o[3]);
}

// ---------------------------------------------------------------------------
extern "C" void kernel_launch(void* const* d_in, const int* in_sizes, int n_in,
                              void* d_out, int out_size, void* d_ws, size_t ws_size,
                              hipStream_t stream)
{
    (void)in_sizes; (void)n_in; (void)out_size; (void)ws_size;
    const float* x    = (const float*)d_in[0];
    const int*   ei   = (const int*)  d_in[1];
    const float* ea   = (const float*)d_in[2];
    const float* Wl   = (const float*)d_in[3];
    const float* bl   = (const float*)d_in[4];
    const float* Wr   = (const float*)d_in[5];
    const float* br   = (const float*)d_in[6];
    const float* We   = (const float*)d_in[7];
    const float* att  = (const float*)d_in[8];
    const float* gamma= (const float*)d_in[10];
    const float* beta = (const float*)d_in[11];
    float* out = (float*)d_out;

    char* wsb = (char*)d_ws;
    size_t o = 0;
    auto take = [&](size_t bytes) -> char* {
        char* p = wsb + o;
        o += (bytes + 255) & ~size_t(255);
        return p;
    };
    unsigned short* xlbf = (unsigned short*)take(sizeof(unsigned short) * NN * HCD);
    float* xr      = (float*)take(sizeof(float) * NN * HCD);
    float* out_pre = (float*)take(sizeof(float) * NN * HCD);
    int2*  csr     = (int2*) take(sizeof(int2)  * NE);
    int*   offs    = (int*)  take(sizeof(int)   * (NN + 1));
    int*   bbase   = (int*)  take(sizeof(int)   * 256);
    size_t zbytes  = sizeof(float) * 2 * HCD + sizeof(int) * NBKT;
    char*  zbase   = take(zbytes);
    float* stats   = (float*)zbase;
    int*   gcur    = (int*)(stats + 2 * HCD);

    // staging aliases out_pre (dead until node_kernel; csr_build finishes first)
    int2*  stg     = (int2*)out_pre;

    hipMemsetAsync(zbase, 0, zbytes, stream);

    const int* srcI = ei;
    const int* dstI = ei + NE;

    gemm_mfma<<<dim3((NN + BM - 1) / BM, 2), 256, 49152, stream>>>(
        x, Wl, Wr, bl, br, xlbf, xr);
    bucket_kernel<<<B1B, 256, 0, stream>>>(srcI, dstI, ea, gcur, stg);
    bscan<<<1, 256, 0, stream>>>(gcur, bbase, offs);
    csr_build<<<NBKT, 256, 0, stream>>>(stg, gcur, bbase, offs, csr);
    node_kernel<<<(NN + 3) / 4, 256, 0, stream>>>(xlbf, xr, We, att, offs, csr, out_pre);
    bnstat_kernel<<<512, 128, 0, stream>>>(out_pre, stats);
    bn_elu_kernel<<<(NN * HCD / 4 + 255) / 256, 256, 0, stream>>>(out_pre, stats,
                                                                  gamma, beta, out);
}